// Round 15
// baseline (417.325 us; speedup 1.0000x reference)
//
#include <hip/hip_runtime.h>

#define N_NODES 100000
#define N_EDGES 3200000
#define NFEAT 256
#define HID 32
#define NCLASS 16

#define NB 64
#define CHUNK (N_EDGES / NB)              // 50000 exactly
#define RN2 32768                         // nodes per range (u16-packed, 64KB LDS)
#define NR2 ((N_NODES + RN2 - 1) / RN2)   // 4

#define SCAN_TPB 256
#define SCAN_EPB 1024
#define SCAN_NBLK ((N_NODES + SCAN_EPB - 1) / SCAN_EPB)   // 98

#define XPAD 133   // 133 % 32 = 5 -> staging writes 2-way max, xv reads conflict-free

typedef float f4nt __attribute__((ext_vector_type(4)));

// bf16 round-to-nearest-even pack / unpack
__device__ inline unsigned short f2bf(float f) {
    unsigned u = __float_as_uint(f);
    u += 0x7FFFu + ((u >> 16) & 1u);
    return (unsigned short)(u >> 16);
}
__device__ inline float bf2f(unsigned short s) {
    return __uint_as_float((unsigned)s << 16);
}
// unpack 8 bf16 (one uint4) -> 8 floats; memory order: low ushort = even idx
__device__ inline void bf8_unpack(uint4 g, float* f) {
    f[0] = __uint_as_float(g.x << 16); f[1] = __uint_as_float(g.x & 0xFFFF0000u);
    f[2] = __uint_as_float(g.y << 16); f[3] = __uint_as_float(g.y & 0xFFFF0000u);
    f[4] = __uint_as_float(g.z << 16); f[5] = __uint_as_float(g.z & 0xFFFF0000u);
    f[6] = __uint_as_float(g.w << 16); f[7] = __uint_as_float(g.w & 0xFFFF0000u);
}
// non-temporal float2 load (streaming: don't retain in L2)
__device__ inline float2 nt_load2(const float2* p) {
    unsigned long long u = __builtin_nontemporal_load((const unsigned long long*)p);
    float2 v;
    v.x = __uint_as_float((unsigned)u);
    v.y = __uint_as_float((unsigned)(u >> 32));
    return v;
}
__device__ inline void nt_store4(float* p, float a, float b, float c, float d) {
    f4nt t; t.x = a; t.y = b; t.z = c; t.w = d;
    __builtin_nontemporal_store(t, (f4nt*)p);
}

// ---- count: grid (NB chunks x NR2 ranges), u16-packed LDS histogram ----
__global__ __launch_bounds__(1024) void k_count(const int* __restrict__ col,
                                                unsigned* __restrict__ H) {
    __shared__ unsigned hist[RN2 / 2];    // 16384 u32 = 64KB, 2 u16 counters/word
    int t = threadIdx.x, b = blockIdx.x, r = blockIdx.y;
    int base = r * RN2;
    const int* cc = col + (size_t)b * CHUNK;
    for (int i = t; i < RN2 / 2; i += 1024) hist[i] = 0;
    __syncthreads();
    for (int i = t; i < CHUNK; i += 1024) {
        unsigned d = (unsigned)cc[i] - (unsigned)base;
        if (d < RN2) atomicAdd(&hist[d >> 1], 1u << ((d & 1) * 16));
    }
    __syncthreads();
    int lim = min(RN2, N_NODES - base);
    unsigned* Hb = H + (size_t)b * N_NODES;
    for (int i = t; i < lim; i += 1024)
        Hb[base + i] = (hist[i >> 1] >> ((i & 1) * 16)) & 0xFFFFu;
}

// ---------------- cnt_total[n] = sum_b H[b][n] (coalesced per b) ----------------
__global__ void k_rowsum(const unsigned* __restrict__ H, int* __restrict__ cnt) {
    int n = blockIdx.x * 256 + threadIdx.x;
    if (n >= N_NODES) return;
    unsigned s = 0;
    #pragma unroll 8
    for (int b = 0; b < NB; ++b) s += H[(size_t)b * N_NODES + n];
    cnt[n] = (int)s;
}

// ---------------- exclusive scan of counts -> offs (3 kernels) ----------------
__global__ __launch_bounds__(SCAN_TPB) void k_scanA(const int* __restrict__ cnt,
                                                    int* __restrict__ offs,
                                                    int* __restrict__ bsum) {
    __shared__ int s[SCAN_TPB];
    int t = threadIdx.x;
    int base = blockIdx.x * SCAN_EPB + t * 4;
    int v0 = (base + 0 < N_NODES) ? cnt[base + 0] : 0;
    int v1 = (base + 1 < N_NODES) ? cnt[base + 1] : 0;
    int v2 = (base + 2 < N_NODES) ? cnt[base + 2] : 0;
    int v3 = (base + 3 < N_NODES) ? cnt[base + 3] : 0;
    int sum = v0 + v1 + v2 + v3;
    s[t] = sum;
    __syncthreads();
    for (int off = 1; off < SCAN_TPB; off <<= 1) {
        int x = (t >= off) ? s[t - off] : 0;
        __syncthreads();
        s[t] += x;
        __syncthreads();
    }
    int excl = s[t] - sum;
    if (t == SCAN_TPB - 1) bsum[blockIdx.x] = s[t];
    int run = excl;
    if (base + 0 < N_NODES) offs[base + 0] = run; run += v0;
    if (base + 1 < N_NODES) offs[base + 1] = run; run += v1;
    if (base + 2 < N_NODES) offs[base + 2] = run; run += v2;
    if (base + 3 < N_NODES) offs[base + 3] = run;
}

__global__ __launch_bounds__(128) void k_scanB(int* __restrict__ bsum) {
    __shared__ int s[128];
    int t = threadIdx.x;
    int v = (t < SCAN_NBLK) ? bsum[t] : 0;
    s[t] = v;
    __syncthreads();
    for (int off = 1; off < 128; off <<= 1) {
        int x = (t >= off) ? s[t - off] : 0;
        __syncthreads();
        s[t] += x;
        __syncthreads();
    }
    if (t < SCAN_NBLK) bsum[t] = s[t] - v;   // exclusive
}

__global__ __launch_bounds__(SCAN_TPB) void k_scanC(int* __restrict__ offs,
                                                    const int* __restrict__ bsum) {
    int t = threadIdx.x;
    int add = bsum[blockIdx.x];
    int base = blockIdx.x * SCAN_EPB + t * 4;
    #pragma unroll
    for (int i = 0; i < 4; ++i) {
        int idx = base + i;
        if (idx < N_NODES) offs[idx] += add;
    }
    if (blockIdx.x == 0 && t == 0) offs[N_NODES] = N_EDGES;
}

// ---- H[b][n] -> base[b][n] = offs[n] + sum_{b'<b} H[b'][n], in place ----
__global__ void k_bprefix(unsigned* __restrict__ H, const int* __restrict__ offs) {
    int n = blockIdx.x * 256 + threadIdx.x;
    if (n >= N_NODES) return;
    unsigned run = (unsigned)offs[n];
    for (int b = 0; b < NB; ++b) {
        size_t idx = (size_t)b * N_NODES + n;
        unsigned v = H[idx];
        H[idx] = run;
        run += v;
    }
}

// ---- place: grid (NB x NR2), u16-packed rank replay -> perm ----
__global__ __launch_bounds__(1024) void k_place(const int* __restrict__ col,
                                                const unsigned* __restrict__ B,
                                                unsigned* __restrict__ perm) {
    __shared__ unsigned rk[RN2 / 2];      // 64KB
    int t = threadIdx.x, b = blockIdx.x, r = blockIdx.y;
    int base = r * RN2;
    size_t eb = (size_t)b * CHUNK;
    const unsigned* Bb = B + (size_t)b * N_NODES;
    for (int i = t; i < RN2 / 2; i += 1024) rk[i] = 0;
    __syncthreads();
    for (int i = t; i < CHUNK; i += 1024) {
        int c = col[eb + i];
        unsigned d = (unsigned)c - (unsigned)base;
        if (d < RN2) {
            unsigned old = atomicAdd(&rk[d >> 1], 1u << ((d & 1) * 16));
            unsigned rr = (old >> ((d & 1) * 16)) & 0xFFFFu;
            perm[eb + i] = Bb[c] + rr;
        }
    }
}

// ---- emit: coalesced read of row/w/perm, scattered 8B write of ein ----
__global__ void k_emit(const int* __restrict__ row, const float* __restrict__ w,
                       const unsigned* __restrict__ perm, float2* __restrict__ ein) {
    int e = blockIdx.x * 256 + threadIdx.x;
    if (e < N_EDGES) ein[perm[e]] = make_float2(__int_as_float(row[e]), w[e]);
}

// ---------------- deg from CSR (segment sum of w) -> dinv ----------------
__global__ void k_deg(const float2* __restrict__ ein, const int* __restrict__ offs,
                      float* __restrict__ dinv) {
    int idx = blockIdx.x * 256 + threadIdx.x;   // N*4
    int n = idx >> 2, l = idx & 3;
    if (n >= N_NODES) return;
    int s = offs[n], e = offs[n + 1];
    float sum = 0.f;
    for (int p = s + l; p < e; p += 4) sum += nt_load2(&ein[p]).y;
    sum += __shfl_xor(sum, 1, 4);
    sum += __shfl_xor(sum, 2, 4);
    if (l == 0) dinv[n] = rsqrtf(1.0f + sum);   // deg = 1 (self-loop) + sum >= 1
}

// ---- GEMM1 split-K=2: 128-row tile, TM4 TN4, k-chunk 32, bf16 partial out ----
__global__ __launch_bounds__(256) void k_gemm1s(const float* __restrict__ x,
                                                const float* __restrict__ W1,
                                                unsigned short* __restrict__ xwp) {
    __shared__ float sWc[32 * HID];       // 4KB
    __shared__ float sX[32 * XPAD];       // 17KB -> total 21.2KB -> 7 blocks/CU
    int t = threadIdx.x;
    long rowbase = (long)blockIdx.x * 128;
    int kbase = blockIdx.y * 128;
    unsigned short* xw = xwp + (size_t)blockIdx.y * N_NODES * HID;
    int tr = t >> 3;                      // 0..31 (4 rows each)
    int tc = t & 7;                       // 0..7  (4 cols each)
    float acc[4][4] = {};
    for (int k0 = kbase; k0 < kbase + 128; k0 += 32) {
        *(float4*)&sWc[t * 4] = *(const float4*)&W1[k0 * HID + t * 4];
        #pragma unroll
        for (int p = 0; p < 4; ++p) {
            int rt = (t >> 3) + p * 32;   // 0..127
            int kk = (t & 7) * 4;         // proven conflict-free staging class
            long grow = rowbase + rt;
            float4 v = make_float4(0.f, 0.f, 0.f, 0.f);
            if (grow < N_NODES) v = *(const float4*)&x[grow * NFEAT + k0 + kk];
            sX[(kk + 0) * XPAD + rt] = v.x; sX[(kk + 1) * XPAD + rt] = v.y;
            sX[(kk + 2) * XPAD + rt] = v.z; sX[(kk + 3) * XPAD + rt] = v.w;
        }
        __syncthreads();
        #pragma unroll 8
        for (int kk = 0; kk < 32; ++kk) {
            float xv[4], wv[4];
            xv[0] = sX[kk * XPAD + tr * 4 + 0];
            xv[1] = sX[kk * XPAD + tr * 4 + 1];
            xv[2] = sX[kk * XPAD + tr * 4 + 2];
            xv[3] = sX[kk * XPAD + tr * 4 + 3];
            *(float4*)&wv[0] = *(float4*)&sWc[kk * HID + tc * 4];
            #pragma unroll
            for (int m = 0; m < 4; ++m)
                #pragma unroll
                for (int n = 0; n < 4; ++n)
                    acc[m][n] = fmaf(xv[m], wv[n], acc[m][n]);
        }
        __syncthreads();
    }
    #pragma unroll
    for (int m = 0; m < 4; ++m) {
        long r = rowbase + tr * 4 + m;
        if (r < N_NODES) {
            ushort4 o;
            o.x = f2bf(acc[m][0]); o.y = f2bf(acc[m][1]);
            o.z = f2bf(acc[m][2]); o.w = f2bf(acc[m][3]);
            *(ushort4*)&xw[r * HID + tc * 4] = o;
        }
    }
}

// ---- combine 2 bf16 split-K partials -> TWO half-feature tables (L2-sized) ----
__global__ void k_comb(const unsigned short* __restrict__ xwp,
                       ushort4* __restrict__ lo, ushort4* __restrict__ hi) {
    int i = blockIdx.x * 256 + threadIdx.x;   // N*HID/4 = 800000 exact
    const ushort4* p0 = (const ushort4*)xwp;
    const ushort4* p1 = p0 + 800000;
    ushort4 a = p0[i], b = p1[i];
    ushort4 o;
    o.x = f2bf(bf2f(a.x) + bf2f(b.x));
    o.y = f2bf(bf2f(a.y) + bf2f(b.y));
    o.z = f2bf(bf2f(a.z) + bf2f(b.z));
    o.w = f2bf(bf2f(a.w) + bf2f(b.w));
    int n = i >> 3, c = i & 7;                // quad c covers cols c*4..c*4+3
    if (c < 4) lo[(n << 2) + c] = o;          // features 0..15
    else       hi[(n << 2) + (c - 4)] = o;    // features 16..31
}

// ---- gather1 half-pass: 2 lanes/node, 16-deep MLP, nt streams, L2-kept table ----
__global__ __launch_bounds__(256) void k_gather1h(const unsigned short* __restrict__ tab,
                                                  const float* __restrict__ dinv,
                                                  const float2* __restrict__ ein,
                                                  const int* __restrict__ offs,
                                                  const float* __restrict__ b1,
                                                  float* __restrict__ h, int c0) {
    int idx = blockIdx.x * 256 + threadIdx.x;   // over N*2
    int n = idx >> 1, l = idx & 1;
    if (n >= N_NODES) return;
    const uint4* xb = (const uint4*)tab;        // 2 uint4 (8 bf16 each) per 16-feat row
    float di = dinv[n];
    float acc[8], f[8];
    bf8_unpack(xb[(long)n * 2 + l], f);
    #pragma unroll
    for (int k = 0; k < 8; ++k) acc[k] = f[k] * di;
    int s = offs[n], e = offs[n + 1];
    for (int p0 = s; p0 < e; p0 += 16) {
        float2 pr[8];
        int rr[8];
        #pragma unroll
        for (int k = 0; k < 8; ++k) {
            int pl = p0 + k * 2 + l;
            pr[k] = (pl < e) ? nt_load2(&ein[pl]) : make_float2(__int_as_float(n), 0.f);
            rr[k] = __float_as_int(pr[k].x);
            pr[k].y *= dinv[rr[k]];
        }
        #pragma unroll
        for (int k = 0; k < 8; ++k) {
            #pragma unroll
            for (int j = 0; j < 2; ++j) {
                int r = __shfl(rr[k], j, 2);
                float nm = __shfl(pr[k].y, j, 2);
                bf8_unpack(xb[(long)r * 2 + l], f);
                #pragma unroll
                for (int q = 0; q < 8; ++q) acc[q] = fmaf(f[q], nm, acc[q]);
            }
        }
    }
    int fo = c0 + l * 8;
    float4 bb0 = *(const float4*)&b1[fo];
    float4 bb1 = *(const float4*)&b1[fo + 4];
    nt_store4(&h[(long)n * HID + fo],
              fmaxf(fmaf(acc[0], di, bb0.x), 0.f), fmaxf(fmaf(acc[1], di, bb0.y), 0.f),
              fmaxf(fmaf(acc[2], di, bb0.z), 0.f), fmaxf(fmaf(acc[3], di, bb0.w), 0.f));
    nt_store4(&h[(long)n * HID + fo + 4],
              fmaxf(fmaf(acc[4], di, bb1.x), 0.f), fmaxf(fmaf(acc[5], di, bb1.y), 0.f),
              fmaxf(fmaf(acc[6], di, bb1.z), 0.f), fmaxf(fmaf(acc[7], di, bb1.w), 0.f));
}

// ---------------- GEMM2: hw = h @ W2 -> bf16 table ----------------
__global__ __launch_bounds__(256) void k_gemm2(const float* __restrict__ h,
                                               const float* __restrict__ W2,
                                               unsigned short* __restrict__ hwb) {
    __shared__ float sH[64][33];
    __shared__ float sW2[HID * NCLASS];
    int t = threadIdx.x;
    if (t < 128) {
        int idx = t * 4;
        *(float4*)&sW2[idx] = *(const float4*)&W2[idx];
    }
    long base = (long)blockIdx.x * 64;
    #pragma unroll
    for (int i = 0; i < 2; ++i) {
        int idx = t + i * 256;
        int rt = idx >> 3, kk = (idx & 7) * 4;
        long gr = base + rt;
        float4 v = make_float4(0.f, 0.f, 0.f, 0.f);
        if (gr < N_NODES) v = *(const float4*)&h[gr * HID + kk];
        sH[rt][kk + 0] = v.x; sH[rt][kk + 1] = v.y;
        sH[rt][kk + 2] = v.z; sH[rt][kk + 3] = v.w;
    }
    __syncthreads();
    int r = t >> 2, c4 = (t & 3) * 4;
    float acc[4] = {};
    #pragma unroll
    for (int k = 0; k < HID; ++k) {
        float hv = sH[r][k];
        float wv[4];
        *(float4*)&wv[0] = *(float4*)&sW2[k * NCLASS + c4];
        #pragma unroll
        for (int n = 0; n < 4; ++n) acc[n] = fmaf(hv, wv[n], acc[n]);
    }
    long gr = base + r;
    if (gr < N_NODES) {
        ushort4 o;
        o.x = f2bf(acc[0]); o.y = f2bf(acc[1]);
        o.z = f2bf(acc[2]); o.w = f2bf(acc[3]);
        *(ushort4*)&hwb[gr * NCLASS + c4] = o;
    }
}

// ---- gather layer 2: 2 lanes/node, 16-deep MLP, nt streams ----
__global__ __launch_bounds__(256) void k_gather2(const unsigned short* __restrict__ hwb,
                                                 const float* __restrict__ dinv,
                                                 const float2* __restrict__ ein,
                                                 const int* __restrict__ offs,
                                                 const float* __restrict__ b2,
                                                 float* __restrict__ out) {
    int idx = blockIdx.x * 256 + threadIdx.x;   // over N*2
    int n = idx >> 1, l = idx & 1;
    if (n >= N_NODES) return;
    int c8 = l * 8;
    const uint4* hb = (const uint4*)hwb;        // 2 uint4 per 16-class row
    float di = dinv[n];
    float acc[8], f[8];
    bf8_unpack(hb[(long)n * 2 + l], f);
    #pragma unroll
    for (int k = 0; k < 8; ++k) acc[k] = f[k] * di;
    int s = offs[n], e = offs[n + 1];
    for (int p0 = s; p0 < e; p0 += 16) {
        float2 pr[8];
        int rr[8];
        #pragma unroll
        for (int k = 0; k < 8; ++k) {
            int pl = p0 + k * 2 + l;
            pr[k] = (pl < e) ? nt_load2(&ein[pl]) : make_float2(__int_as_float(n), 0.f);
            rr[k] = __float_as_int(pr[k].x);
            pr[k].y *= dinv[rr[k]];
        }
        #pragma unroll
        for (int k = 0; k < 8; ++k) {
            #pragma unroll
            for (int j = 0; j < 2; ++j) {
                int r = __shfl(rr[k], j, 2);
                float nm = __shfl(pr[k].y, j, 2);
                bf8_unpack(hb[(long)r * 2 + l], f);
                #pragma unroll
                for (int q = 0; q < 8; ++q) acc[q] = fmaf(f[q], nm, acc[q]);
            }
        }
    }
    float4 bb0 = *(const float4*)&b2[c8];
    float4 bb1 = *(const float4*)&b2[c8 + 4];
    float v[8];
    v[0] = fmaf(acc[0], di, bb0.x); v[1] = fmaf(acc[1], di, bb0.y);
    v[2] = fmaf(acc[2], di, bb0.z); v[3] = fmaf(acc[3], di, bb0.w);
    v[4] = fmaf(acc[4], di, bb1.x); v[5] = fmaf(acc[5], di, bb1.y);
    v[6] = fmaf(acc[6], di, bb1.z); v[7] = fmaf(acc[7], di, bb1.w);
    float m = v[0];
    #pragma unroll
    for (int k = 1; k < 8; ++k) m = fmaxf(m, v[k]);
    m = fmaxf(m, __shfl_xor(m, 1, 2));
    float sum = 0.f;
    #pragma unroll
    for (int k = 0; k < 8; ++k) sum += __expf(v[k] - m);
    sum += __shfl_xor(sum, 1, 2);
    float ls = m + __logf(sum);
    nt_store4(&out[(long)n * NCLASS + c8], v[0] - ls, v[1] - ls, v[2] - ls, v[3] - ls);
    nt_store4(&out[(long)n * NCLASS + c8 + 4], v[4] - ls, v[5] - ls, v[6] - ls, v[7] - ls);
}

extern "C" void kernel_launch(void* const* d_in, const int* in_sizes, int n_in,
                              void* d_out, int out_size, void* d_ws, size_t ws_size,
                              hipStream_t stream) {
    const float* x  = (const float*)d_in[0];
    const int*   ei = (const int*)d_in[1];
    const float* w  = (const float*)d_in[2];
    const float* W1 = (const float*)d_in[3];
    const float* b1 = (const float*)d_in[4];
    const float* W2 = (const float*)d_in[5];
    const float* b2 = (const float*)d_in[6];
    float* out = (float*)d_out;

    const int* row = ei;
    const int* col = ei + N_EDGES;

    // Workspace (floats). Tight-aliased; ws footprint ~87MB so inputs (~141MB)
    // + ws stay under the 256MB Infinity Cache (R9 lesson).
    float* ws = (float*)d_ws;
    float2* ein = (float2*)ws;                            // 25.6MB
    unsigned* H = (unsigned*)(ws + 2 * (size_t)N_EDGES);  // NB*N u32 (25.6MB)
    unsigned* perm = (unsigned*)(ws + 2 * (size_t)N_EDGES + (size_t)NB * N_NODES);  // E u32
    float* h = (float*)perm;                              // alias: written after emit+comb
    float* dinv = ws + 2 * (size_t)N_EDGES + (size_t)NB * N_NODES + N_EDGES;  // N
    int* cnt = (int*)(dinv + N_NODES);                    // N
    int* offs = cnt + N_NODES;                            // N+1
    int* bsum = offs + N_NODES + 1;                       // 128
    size_t xwp_off = (size_t)(2 * (size_t)N_EDGES + (size_t)NB * N_NODES + N_EDGES
                              + 3 * N_NODES + 1 + 128);
    xwp_off = (xwp_off + 3) & ~(size_t)3;                 // 16B align
    unsigned short* xwp = (unsigned short*)(ws + xwp_off);               // [2][N*HID] bf16 (12.8MB)
    unsigned short* xwb_lo = (unsigned short*)(ws + xwp_off + 3200000);  // N*16 bf16 (3.2MB)
    unsigned short* xwb_hi = xwb_lo + (size_t)N_NODES * 16;              // N*16 bf16 (3.2MB)
    unsigned short* hwb = xwb_hi + (size_t)N_NODES * 16;                 // N*NCLASS bf16 (3.2MB)

    const int B = 256;

    k_count<<<dim3(NB, NR2), 1024, 0, stream>>>(col, H);
    k_rowsum<<<(N_NODES + B - 1) / B, B, 0, stream>>>(H, cnt);
    k_scanA<<<SCAN_NBLK, SCAN_TPB, 0, stream>>>(cnt, offs, bsum);
    k_scanB<<<1, 128, 0, stream>>>(bsum);
    k_scanC<<<SCAN_NBLK, SCAN_TPB, 0, stream>>>(offs, bsum);
    k_bprefix<<<(N_NODES + B - 1) / B, B, 0, stream>>>(H, offs);
    k_place<<<dim3(NB, NR2), 1024, 0, stream>>>(col, H, perm);
    k_emit<<<(N_EDGES + B - 1) / B, B, 0, stream>>>(row, w, perm, ein);

    k_deg<<<(N_NODES * 4 + B - 1) / B, B, 0, stream>>>(ein, offs, dinv);

    k_gemm1s<<<dim3((N_NODES + 127) / 128, 2), 256, 0, stream>>>(x, W1, xwp);
    k_comb<<<(N_NODES * HID / 4) / B, B, 0, stream>>>(xwp, (ushort4*)xwb_lo, (ushort4*)xwb_hi);
    k_gather1h<<<(N_NODES * 2 + B - 1) / B, B, 0, stream>>>(xwb_lo, dinv, ein, offs, b1, h, 0);
    k_gather1h<<<(N_NODES * 2 + B - 1) / B, B, 0, stream>>>(xwb_hi, dinv, ein, offs, b1, h, 16);

    k_gemm2<<<(N_NODES + 63) / 64, B, 0, stream>>>(h, W2, hwb);
    k_gather2<<<(N_NODES * 2 + B - 1) / B, B, 0, stream>>>(hwb, dinv, ein, offs, b2, out);
}

// Round 16
// 284.440 us; speedup vs baseline: 1.4672x; 1.4672x over previous
//
#include <hip/hip_runtime.h>

#define N_NODES 100000
#define N_EDGES 3200000
#define NFEAT 256
#define HID 32
#define NCLASS 16

#define NB 64
#define CHUNK (N_EDGES / NB)              // 50000 exactly
#define RN2 32768                         // nodes per range (u16-packed, 64KB LDS)
#define NR2 ((N_NODES + RN2 - 1) / RN2)   // 4

#define SCAN_TPB 256
#define SCAN_EPB 1024
#define SCAN_NBLK ((N_NODES + SCAN_EPB - 1) / SCAN_EPB)   // 98

#define XPAD 133   // 133 % 32 = 5 -> staging writes 2-way max, xv reads conflict-free

// bf16 round-to-nearest-even pack / unpack
__device__ inline unsigned short f2bf(float f) {
    unsigned u = __float_as_uint(f);
    u += 0x7FFFu + ((u >> 16) & 1u);
    return (unsigned short)(u >> 16);
}
__device__ inline float bf2f(unsigned short s) {
    return __uint_as_float((unsigned)s << 16);
}
// unpack 8 bf16 (one uint4) -> 8 floats; memory order: low ushort = even idx
__device__ inline void bf8_unpack(uint4 g, float* f) {
    f[0] = __uint_as_float(g.x << 16); f[1] = __uint_as_float(g.x & 0xFFFF0000u);
    f[2] = __uint_as_float(g.y << 16); f[3] = __uint_as_float(g.y & 0xFFFF0000u);
    f[4] = __uint_as_float(g.z << 16); f[5] = __uint_as_float(g.z & 0xFFFF0000u);
    f[6] = __uint_as_float(g.w << 16); f[7] = __uint_as_float(g.w & 0xFFFF0000u);
}

// ---- count + rank record: grid (NB chunks x NR2 ranges), u16-packed LDS hist ----
__global__ __launch_bounds__(1024) void k_count(const int* __restrict__ col,
                                                unsigned* __restrict__ H,
                                                unsigned short* __restrict__ pos) {
    __shared__ unsigned hist[RN2 / 2];    // 16384 u32 = 64KB, 2 u16 counters/word
    int t = threadIdx.x, b = blockIdx.x, r = blockIdx.y;
    int base = r * RN2;
    const int* cc = col + (size_t)b * CHUNK;
    unsigned short* pp = pos + (size_t)b * CHUNK;
    for (int i = t; i < RN2 / 2; i += 1024) hist[i] = 0;
    __syncthreads();
    for (int i = t; i < CHUNK; i += 1024) {
        unsigned d = (unsigned)cc[i] - (unsigned)base;
        if (d < RN2) {
            unsigned old = atomicAdd(&hist[d >> 1], 1u << ((d & 1) * 16));
            pp[i] = (unsigned short)((old >> ((d & 1) * 16)) & 0xFFFFu);
        }
    }
    __syncthreads();
    int lim = min(RN2, N_NODES - base);
    unsigned* Hb = H + (size_t)b * N_NODES;
    for (int i = t; i < lim; i += 1024)
        Hb[base + i] = (hist[i >> 1] >> ((i & 1) * 16)) & 0xFFFFu;
}

// ---------------- cnt_total[n] = sum_b H[b][n] (coalesced per b) ----------------
__global__ void k_rowsum(const unsigned* __restrict__ H, int* __restrict__ cnt) {
    int n = blockIdx.x * 256 + threadIdx.x;
    if (n >= N_NODES) return;
    unsigned s = 0;
    #pragma unroll 8
    for (int b = 0; b < NB; ++b) s += H[(size_t)b * N_NODES + n];
    cnt[n] = (int)s;
}

// ---------------- exclusive scan of counts -> offs (3 kernels) ----------------
__global__ __launch_bounds__(SCAN_TPB) void k_scanA(const int* __restrict__ cnt,
                                                    int* __restrict__ offs,
                                                    int* __restrict__ bsum) {
    __shared__ int s[SCAN_TPB];
    int t = threadIdx.x;
    int base = blockIdx.x * SCAN_EPB + t * 4;
    int v0 = (base + 0 < N_NODES) ? cnt[base + 0] : 0;
    int v1 = (base + 1 < N_NODES) ? cnt[base + 1] : 0;
    int v2 = (base + 2 < N_NODES) ? cnt[base + 2] : 0;
    int v3 = (base + 3 < N_NODES) ? cnt[base + 3] : 0;
    int sum = v0 + v1 + v2 + v3;
    s[t] = sum;
    __syncthreads();
    for (int off = 1; off < SCAN_TPB; off <<= 1) {
        int x = (t >= off) ? s[t - off] : 0;
        __syncthreads();
        s[t] += x;
        __syncthreads();
    }
    int excl = s[t] - sum;
    if (t == SCAN_TPB - 1) bsum[blockIdx.x] = s[t];
    int run = excl;
    if (base + 0 < N_NODES) offs[base + 0] = run; run += v0;
    if (base + 1 < N_NODES) offs[base + 1] = run; run += v1;
    if (base + 2 < N_NODES) offs[base + 2] = run; run += v2;
    if (base + 3 < N_NODES) offs[base + 3] = run;
}

__global__ __launch_bounds__(128) void k_scanB(int* __restrict__ bsum) {
    __shared__ int s[128];
    int t = threadIdx.x;
    int v = (t < SCAN_NBLK) ? bsum[t] : 0;
    s[t] = v;
    __syncthreads();
    for (int off = 1; off < 128; off <<= 1) {
        int x = (t >= off) ? s[t - off] : 0;
        __syncthreads();
        s[t] += x;
        __syncthreads();
    }
    if (t < SCAN_NBLK) bsum[t] = s[t] - v;   // exclusive
}

__global__ __launch_bounds__(SCAN_TPB) void k_scanC(int* __restrict__ offs,
                                                    const int* __restrict__ bsum) {
    int t = threadIdx.x;
    int add = bsum[blockIdx.x];
    int base = blockIdx.x * SCAN_EPB + t * 4;
    #pragma unroll
    for (int i = 0; i < 4; ++i) {
        int idx = base + i;
        if (idx < N_NODES) offs[idx] += add;
    }
    if (blockIdx.x == 0 && t == 0) offs[N_NODES] = N_EDGES;
}

// ---- H[b][n] -> base[b][n] = offs[n] + sum_{b'<b} H[b'][n], in place ----
__global__ void k_bprefix(unsigned* __restrict__ H, const int* __restrict__ offs) {
    int n = blockIdx.x * 256 + threadIdx.x;
    if (n >= N_NODES) return;
    unsigned run = (unsigned)offs[n];
    for (int b = 0; b < NB; ++b) {
        size_t idx = (size_t)b * N_NODES + n;
        unsigned v = H[idx];
        H[idx] = run;
        run += v;
    }
}

// ---- emit: p = base[b][col] + pos (no replay pass), scattered 8B ein write ----
__global__ void k_emit(const int* __restrict__ row, const int* __restrict__ col,
                       const float* __restrict__ w, const unsigned* __restrict__ B,
                       const unsigned short* __restrict__ pos,
                       float2* __restrict__ ein) {
    int e = blockIdx.x * 256 + threadIdx.x;
    if (e >= N_EDGES) return;
    int b = e / CHUNK;                    // const divide -> magic mul
    int c = col[e];
    unsigned p = B[(size_t)b * N_NODES + c] + (unsigned)pos[e];
    ein[p] = make_float2(__int_as_float(row[e]), w[e]);
}

// ---------------- deg from CSR (segment sum of w) -> dinv ----------------
__global__ void k_deg(const float2* __restrict__ ein, const int* __restrict__ offs,
                      float* __restrict__ dinv) {
    int idx = blockIdx.x * 256 + threadIdx.x;   // N*4
    int n = idx >> 2, l = idx & 3;
    if (n >= N_NODES) return;
    int s = offs[n], e = offs[n + 1];
    float sum = 0.f;
    for (int p = s + l; p < e; p += 4) sum += ein[p].y;
    sum += __shfl_xor(sum, 1, 4);
    sum += __shfl_xor(sum, 2, 4);
    if (l == 0) dinv[n] = rsqrtf(1.0f + sum);   // deg = 1 (self-loop) + sum >= 1
}

// ---- GEMM1 split-K=2: 128-row tile, TM4 TN4, k-chunk 32, bf16 partial out ----
__global__ __launch_bounds__(256) void k_gemm1s(const float* __restrict__ x,
                                                const float* __restrict__ W1,
                                                unsigned short* __restrict__ xwp) {
    __shared__ float sWc[32 * HID];       // 4KB
    __shared__ float sX[32 * XPAD];       // 17KB -> total 21.2KB -> 7 blocks/CU
    int t = threadIdx.x;
    long rowbase = (long)blockIdx.x * 128;
    int kbase = blockIdx.y * 128;
    unsigned short* xw = xwp + (size_t)blockIdx.y * N_NODES * HID;
    int tr = t >> 3;                      // 0..31 (4 rows each)
    int tc = t & 7;                       // 0..7  (4 cols each)
    float acc[4][4] = {};
    for (int k0 = kbase; k0 < kbase + 128; k0 += 32) {
        *(float4*)&sWc[t * 4] = *(const float4*)&W1[k0 * HID + t * 4];
        #pragma unroll
        for (int p = 0; p < 4; ++p) {
            int rt = (t >> 3) + p * 32;   // 0..127
            int kk = (t & 7) * 4;         // proven conflict-free staging class
            long grow = rowbase + rt;
            float4 v = make_float4(0.f, 0.f, 0.f, 0.f);
            if (grow < N_NODES) v = *(const float4*)&x[grow * NFEAT + k0 + kk];
            sX[(kk + 0) * XPAD + rt] = v.x; sX[(kk + 1) * XPAD + rt] = v.y;
            sX[(kk + 2) * XPAD + rt] = v.z; sX[(kk + 3) * XPAD + rt] = v.w;
        }
        __syncthreads();
        #pragma unroll 8
        for (int kk = 0; kk < 32; ++kk) {
            float xv[4], wv[4];
            xv[0] = sX[kk * XPAD + tr * 4 + 0];
            xv[1] = sX[kk * XPAD + tr * 4 + 1];
            xv[2] = sX[kk * XPAD + tr * 4 + 2];
            xv[3] = sX[kk * XPAD + tr * 4 + 3];
            *(float4*)&wv[0] = *(float4*)&sWc[kk * HID + tc * 4];
            #pragma unroll
            for (int m = 0; m < 4; ++m)
                #pragma unroll
                for (int n = 0; n < 4; ++n)
                    acc[m][n] = fmaf(xv[m], wv[n], acc[m][n]);
        }
        __syncthreads();
    }
    #pragma unroll
    for (int m = 0; m < 4; ++m) {
        long r = rowbase + tr * 4 + m;
        if (r < N_NODES) {
            ushort4 o;
            o.x = f2bf(acc[m][0]); o.y = f2bf(acc[m][1]);
            o.z = f2bf(acc[m][2]); o.w = f2bf(acc[m][3]);
            *(ushort4*)&xw[r * HID + tc * 4] = o;
        }
    }
}

// ---- combine 2 bf16 split-K partials -> bf16 gather table ----
__global__ void k_comb(const unsigned short* __restrict__ xwp,
                       ushort4* __restrict__ xwb) {
    int i = blockIdx.x * 256 + threadIdx.x;   // N*HID/4 = 800000 exact
    const ushort4* p0 = (const ushort4*)xwp;
    const ushort4* p1 = p0 + 800000;
    ushort4 a = p0[i], b = p1[i];
    ushort4 o;
    o.x = f2bf(bf2f(a.x) + bf2f(b.x));
    o.y = f2bf(bf2f(a.y) + bf2f(b.y));
    o.z = f2bf(bf2f(a.z) + bf2f(b.z));
    o.w = f2bf(bf2f(a.w) + bf2f(b.w));
    xwb[i] = o;
}

// ---- gather layer 1: 8 lanes/node, bf16 table (R12's 64us config) ----
__global__ __launch_bounds__(256) void k_gather1(const unsigned short* __restrict__ xwb,
                                                 const float* __restrict__ dinv,
                                                 const float2* __restrict__ ein,
                                                 const int* __restrict__ offs,
                                                 const float* __restrict__ b1,
                                                 float* __restrict__ h) {
    int idx = blockIdx.x * 256 + threadIdx.x;   // N*8 exact
    int n = idx >> 3, l = idx & 7;
    int c4 = l * 4;
    const ushort4* xb = (const ushort4*)xwb;    // 8 ushort4 per row
    float di = dinv[n];
    ushort4 q = xb[(long)n * 8 + l];
    float4 acc = make_float4(bf2f(q.x) * di, bf2f(q.y) * di,
                             bf2f(q.z) * di, bf2f(q.w) * di);
    int s = offs[n], e = offs[n + 1];
    for (int p0 = s; p0 < e; p0 += 8) {
        int pl = p0 + l;
        float2 pr = (pl < e) ? ein[pl] : make_float2(__int_as_float(n), 0.f);
        int ri = __float_as_int(pr.x);
        pr.y *= dinv[ri];                 // fold dinv[src] before broadcast
        #pragma unroll
        for (int j = 0; j < 8; ++j) {
            int r = __shfl(ri, j, 8);
            float nm = __shfl(pr.y, j, 8);
            ushort4 g = xb[(long)r * 8 + l];
            acc.x = fmaf(bf2f(g.x), nm, acc.x);
            acc.y = fmaf(bf2f(g.y), nm, acc.y);
            acc.z = fmaf(bf2f(g.z), nm, acc.z);
            acc.w = fmaf(bf2f(g.w), nm, acc.w);
        }
    }
    float4 bb = *(const float4*)&b1[c4];
    acc.x = fmaxf(fmaf(acc.x, di, bb.x), 0.f);
    acc.y = fmaxf(fmaf(acc.y, di, bb.y), 0.f);
    acc.z = fmaxf(fmaf(acc.z, di, bb.z), 0.f);
    acc.w = fmaxf(fmaf(acc.w, di, bb.w), 0.f);
    *(float4*)&h[(long)n * HID + c4] = acc;
}

// ---------------- GEMM2: hw = h @ W2 -> bf16 table ----------------
__global__ __launch_bounds__(256) void k_gemm2(const float* __restrict__ h,
                                               const float* __restrict__ W2,
                                               unsigned short* __restrict__ hwb) {
    __shared__ float sH[64][33];
    __shared__ float sW2[HID * NCLASS];
    int t = threadIdx.x;
    if (t < 128) {
        int idx = t * 4;
        *(float4*)&sW2[idx] = *(const float4*)&W2[idx];
    }
    long base = (long)blockIdx.x * 64;
    #pragma unroll
    for (int i = 0; i < 2; ++i) {
        int idx = t + i * 256;
        int rt = idx >> 3, kk = (idx & 7) * 4;
        long gr = base + rt;
        float4 v = make_float4(0.f, 0.f, 0.f, 0.f);
        if (gr < N_NODES) v = *(const float4*)&h[gr * HID + kk];
        sH[rt][kk + 0] = v.x; sH[rt][kk + 1] = v.y;
        sH[rt][kk + 2] = v.z; sH[rt][kk + 3] = v.w;
    }
    __syncthreads();
    int r = t >> 2, c4 = (t & 3) * 4;
    float acc[4] = {};
    #pragma unroll
    for (int k = 0; k < HID; ++k) {
        float hv = sH[r][k];
        float wv[4];
        *(float4*)&wv[0] = *(float4*)&sW2[k * NCLASS + c4];
        #pragma unroll
        for (int n = 0; n < 4; ++n) acc[n] = fmaf(hv, wv[n], acc[n]);
    }
    long gr = base + r;
    if (gr < N_NODES) {
        ushort4 o;
        o.x = f2bf(acc[0]); o.y = f2bf(acc[1]);
        o.z = f2bf(acc[2]); o.w = f2bf(acc[3]);
        *(ushort4*)&hwb[gr * NCLASS + c4] = o;
    }
}

// ---- gather layer 2: 2 lanes/node x 16B loads, 8-deep, softmax width 2 ----
__global__ __launch_bounds__(256) void k_gather2(const unsigned short* __restrict__ hwb,
                                                 const float* __restrict__ dinv,
                                                 const float2* __restrict__ ein,
                                                 const int* __restrict__ offs,
                                                 const float* __restrict__ b2,
                                                 float* __restrict__ out) {
    int idx = blockIdx.x * 256 + threadIdx.x;   // over N*2
    int n = idx >> 1, l = idx & 1;
    if (n >= N_NODES) return;
    int c8 = l * 8;
    const uint4* hb = (const uint4*)hwb;        // 2 uint4 per 16-class row
    float di = dinv[n];
    float acc[8], f[8];
    bf8_unpack(hb[(long)n * 2 + l], f);
    #pragma unroll
    for (int k = 0; k < 8; ++k) acc[k] = f[k] * di;
    int s = offs[n], e = offs[n + 1];
    for (int p0 = s; p0 < e; p0 += 8) {
        float2 pr[4];
        int rr[4];
        #pragma unroll
        for (int k = 0; k < 4; ++k) {
            int pl = p0 + k * 2 + l;
            pr[k] = (pl < e) ? ein[pl] : make_float2(__int_as_float(n), 0.f);
            rr[k] = __float_as_int(pr[k].x);
            pr[k].y *= dinv[rr[k]];
        }
        #pragma unroll
        for (int k = 0; k < 4; ++k) {
            #pragma unroll
            for (int j = 0; j < 2; ++j) {
                int r = __shfl(rr[k], j, 2);
                float nm = __shfl(pr[k].y, j, 2);
                bf8_unpack(hb[(long)r * 2 + l], f);
                #pragma unroll
                for (int q = 0; q < 8; ++q) acc[q] = fmaf(f[q], nm, acc[q]);
            }
        }
    }
    float4 bb0 = *(const float4*)&b2[c8];
    float4 bb1 = *(const float4*)&b2[c8 + 4];
    float v[8];
    v[0] = fmaf(acc[0], di, bb0.x); v[1] = fmaf(acc[1], di, bb0.y);
    v[2] = fmaf(acc[2], di, bb0.z); v[3] = fmaf(acc[3], di, bb0.w);
    v[4] = fmaf(acc[4], di, bb1.x); v[5] = fmaf(acc[5], di, bb1.y);
    v[6] = fmaf(acc[6], di, bb1.z); v[7] = fmaf(acc[7], di, bb1.w);
    float m = v[0];
    #pragma unroll
    for (int k = 1; k < 8; ++k) m = fmaxf(m, v[k]);
    m = fmaxf(m, __shfl_xor(m, 1, 2));
    float sum = 0.f;
    #pragma unroll
    for (int k = 0; k < 8; ++k) sum += __expf(v[k] - m);
    sum += __shfl_xor(sum, 1, 2);
    float ls = m + __logf(sum);
    float4 o0 = make_float4(v[0] - ls, v[1] - ls, v[2] - ls, v[3] - ls);
    float4 o1 = make_float4(v[4] - ls, v[5] - ls, v[6] - ls, v[7] - ls);
    *(float4*)&out[(long)n * NCLASS + c8] = o0;
    *(float4*)&out[(long)n * NCLASS + c8 + 4] = o1;
}

extern "C" void kernel_launch(void* const* d_in, const int* in_sizes, int n_in,
                              void* d_out, int out_size, void* d_ws, size_t ws_size,
                              hipStream_t stream) {
    const float* x  = (const float*)d_in[0];
    const int*   ei = (const int*)d_in[1];
    const float* w  = (const float*)d_in[2];
    const float* W1 = (const float*)d_in[3];
    const float* b1 = (const float*)d_in[4];
    const float* W2 = (const float*)d_in[5];
    const float* b2 = (const float*)d_in[6];
    float* out = (float*)d_out;

    const int* row = ei;
    const int* col = ei + N_EDGES;

    // Workspace (floats). Tight-aliased; ws footprint ~87MB so inputs (~141MB)
    // + ws stay under the 256MB Infinity Cache (R9 lesson).
    //   pos (E u16) lives in the old perm slot; read last by k_emit, then
    //   h (N*HID f32) is written over the same region by gather1.
    float* ws = (float*)d_ws;
    float2* ein = (float2*)ws;                            // 25.6MB
    unsigned* H = (unsigned*)(ws + 2 * (size_t)N_EDGES);  // NB*N u32 (25.6MB)
    unsigned short* pos = (unsigned short*)(ws + 2 * (size_t)N_EDGES + (size_t)NB * N_NODES);  // E u16
    float* h = (float*)pos;                               // alias: written after emit
    float* dinv = ws + 2 * (size_t)N_EDGES + (size_t)NB * N_NODES + N_EDGES;  // N
    int* cnt = (int*)(dinv + N_NODES);                    // N
    int* offs = cnt + N_NODES;                            // N+1
    int* bsum = offs + N_NODES + 1;                       // 128
    size_t xwp_off = (size_t)(2 * (size_t)N_EDGES + (size_t)NB * N_NODES + N_EDGES
                              + 3 * N_NODES + 1 + 128);
    xwp_off = (xwp_off + 3) & ~(size_t)3;                 // 16B align
    unsigned short* xwp = (unsigned short*)(ws + xwp_off);               // [2][N*HID] bf16 (12.8MB)
    unsigned short* xwb = (unsigned short*)(ws + xwp_off + 3200000);     // N*HID bf16 (6.4MB)
    unsigned short* hwb = xwb + (size_t)N_NODES * HID;                   // N*NCLASS bf16 (3.2MB)

    const int B = 256;

    k_count<<<dim3(NB, NR2), 1024, 0, stream>>>(col, H, pos);
    k_rowsum<<<(N_NODES + B - 1) / B, B, 0, stream>>>(H, cnt);
    k_scanA<<<SCAN_NBLK, SCAN_TPB, 0, stream>>>(cnt, offs, bsum);
    k_scanB<<<1, 128, 0, stream>>>(bsum);
    k_scanC<<<SCAN_NBLK, SCAN_TPB, 0, stream>>>(offs, bsum);
    k_bprefix<<<(N_NODES + B - 1) / B, B, 0, stream>>>(H, offs);
    k_emit<<<(N_EDGES + B - 1) / B, B, 0, stream>>>(row, col, w, H, pos, ein);

    k_deg<<<(N_NODES * 4 + B - 1) / B, B, 0, stream>>>(ein, offs, dinv);

    k_gemm1s<<<dim3((N_NODES + 127) / 128, 2), 256, 0, stream>>>(x, W1, xwp);
    k_comb<<<(N_NODES * HID / 4) / B, B, 0, stream>>>(xwp, (ushort4*)xwb);
    k_gather1<<<(N_NODES * 8) / B, B, 0, stream>>>(xwb, dinv, ein, offs, b1, h);

    k_gemm2<<<(N_NODES + 63) / 64, B, 0, stream>>>(h, W2, hwb);
    k_gather2<<<(N_NODES * 2 + B - 1) / B, B, 0, stream>>>(hwb, dinv, ein, offs, b2, out);
}

// Round 17
// 263.117 us; speedup vs baseline: 1.5861x; 1.0810x over previous
//
#include <hip/hip_runtime.h>

#define N_NODES 100000
#define N_EDGES 3200000
#define NFEAT 256
#define HID 32
#define NCLASS 16

#define NB 64
#define CHUNK (N_EDGES / NB)              // 50000 exactly
#define RN2 32768                         // nodes per range (u16-packed, 64KB LDS)
#define NR2 ((N_NODES + RN2 - 1) / RN2)   // 4
#define BPC 196                           // blocks per chunk in emit (196*256 >= 50000)

#define SCAN_TPB 256
#define SCAN_EPB 1024
#define SCAN_NBLK ((N_NODES + SCAN_EPB - 1) / SCAN_EPB)   // 98

#define XPAD 133   // 133 % 32 = 5 -> staging writes 2-way max, xv reads conflict-free

// bf16 round-to-nearest-even pack / unpack
__device__ inline unsigned short f2bf(float f) {
    unsigned u = __float_as_uint(f);
    u += 0x7FFFu + ((u >> 16) & 1u);
    return (unsigned short)(u >> 16);
}
__device__ inline float bf2f(unsigned short s) {
    return __uint_as_float((unsigned)s << 16);
}
// unpack 8 bf16 (one uint4) -> 8 floats; memory order: low ushort = even idx
__device__ inline void bf8_unpack(uint4 g, float* f) {
    f[0] = __uint_as_float(g.x << 16); f[1] = __uint_as_float(g.x & 0xFFFF0000u);
    f[2] = __uint_as_float(g.y << 16); f[3] = __uint_as_float(g.y & 0xFFFF0000u);
    f[4] = __uint_as_float(g.z << 16); f[5] = __uint_as_float(g.z & 0xFFFF0000u);
    f[6] = __uint_as_float(g.w << 16); f[7] = __uint_as_float(g.w & 0xFFFF0000u);
}

// ---- count + rank record: grid (NB chunks x NR2 ranges), u16-packed LDS hist ----
__global__ __launch_bounds__(1024) void k_count(const int* __restrict__ col,
                                                unsigned* __restrict__ H,
                                                unsigned short* __restrict__ pos) {
    __shared__ unsigned hist[RN2 / 2];    // 16384 u32 = 64KB, 2 u16 counters/word
    int t = threadIdx.x, b = blockIdx.x, r = blockIdx.y;
    int base = r * RN2;
    const int* cc = col + (size_t)b * CHUNK;
    unsigned short* pp = pos + (size_t)b * CHUNK;
    for (int i = t; i < RN2 / 2; i += 1024) hist[i] = 0;
    __syncthreads();
    for (int i = t; i < CHUNK; i += 1024) {
        unsigned d = (unsigned)cc[i] - (unsigned)base;
        if (d < RN2) {
            unsigned old = atomicAdd(&hist[d >> 1], 1u << ((d & 1) * 16));
            pp[i] = (unsigned short)((old >> ((d & 1) * 16)) & 0xFFFFu);
        }
    }
    __syncthreads();
    int lim = min(RN2, N_NODES - base);
    unsigned* Hb = H + (size_t)b * N_NODES;
    for (int i = t; i < lim; i += 1024)
        Hb[base + i] = (hist[i >> 1] >> ((i & 1) * 16)) & 0xFFFFu;
}

// ---- per-node: SP[b][n] = sum_{b'<b} H[b'][n] (u16), cnt[n] = total ----
__global__ void k_prefix16(const unsigned* __restrict__ H,
                           unsigned short* __restrict__ SP, int* __restrict__ cnt) {
    int n = blockIdx.x * 256 + threadIdx.x;
    if (n >= N_NODES) return;
    unsigned run = 0;
    #pragma unroll 8
    for (int b = 0; b < NB; ++b) {
        size_t i = (size_t)b * N_NODES + n;
        unsigned v = H[i];
        SP[i] = (unsigned short)run;
        run += v;
    }
    cnt[n] = (int)run;
}

// ---------------- exclusive scan of counts -> offs (3 kernels) ----------------
__global__ __launch_bounds__(SCAN_TPB) void k_scanA(const int* __restrict__ cnt,
                                                    int* __restrict__ offs,
                                                    int* __restrict__ bsum) {
    __shared__ int s[SCAN_TPB];
    int t = threadIdx.x;
    int base = blockIdx.x * SCAN_EPB + t * 4;
    int v0 = (base + 0 < N_NODES) ? cnt[base + 0] : 0;
    int v1 = (base + 1 < N_NODES) ? cnt[base + 1] : 0;
    int v2 = (base + 2 < N_NODES) ? cnt[base + 2] : 0;
    int v3 = (base + 3 < N_NODES) ? cnt[base + 3] : 0;
    int sum = v0 + v1 + v2 + v3;
    s[t] = sum;
    __syncthreads();
    for (int off = 1; off < SCAN_TPB; off <<= 1) {
        int x = (t >= off) ? s[t - off] : 0;
        __syncthreads();
        s[t] += x;
        __syncthreads();
    }
    int excl = s[t] - sum;
    if (t == SCAN_TPB - 1) bsum[blockIdx.x] = s[t];
    int run = excl;
    if (base + 0 < N_NODES) offs[base + 0] = run; run += v0;
    if (base + 1 < N_NODES) offs[base + 1] = run; run += v1;
    if (base + 2 < N_NODES) offs[base + 2] = run; run += v2;
    if (base + 3 < N_NODES) offs[base + 3] = run;
}

__global__ __launch_bounds__(128) void k_scanB(int* __restrict__ bsum) {
    __shared__ int s[128];
    int t = threadIdx.x;
    int v = (t < SCAN_NBLK) ? bsum[t] : 0;
    s[t] = v;
    __syncthreads();
    for (int off = 1; off < 128; off <<= 1) {
        int x = (t >= off) ? s[t - off] : 0;
        __syncthreads();
        s[t] += x;
        __syncthreads();
    }
    if (t < SCAN_NBLK) bsum[t] = s[t] - v;   // exclusive
}

__global__ __launch_bounds__(SCAN_TPB) void k_scanC(int* __restrict__ offs,
                                                    const int* __restrict__ bsum) {
    int t = threadIdx.x;
    int add = bsum[blockIdx.x];
    int base = blockIdx.x * SCAN_EPB + t * 4;
    #pragma unroll
    for (int i = 0; i < 4; ++i) {
        int idx = base + i;
        if (idx < N_NODES) offs[idx] += add;
    }
    if (blockIdx.x == 0 && t == 0) offs[N_NODES] = N_EDGES;
}

// ---- emit, XCD-chunk-affine: blocks on one XCD walk that XCD's 8 chunks in
// order, so the chunk's SP row (200KB) + offs (400KB) stay L2-resident. ----
__global__ __launch_bounds__(256) void k_emit(const int* __restrict__ row,
                                              const int* __restrict__ col,
                                              const float* __restrict__ w,
                                              const int* __restrict__ offs,
                                              const unsigned short* __restrict__ SP,
                                              const unsigned short* __restrict__ pos,
                                              float2* __restrict__ ein) {
    int bid = blockIdx.x;
    int xcd = bid & 7;
    int q = bid >> 3;                 // 0 .. 8*BPC-1
    int m = q / BPC;                  // which of this XCD's 8 chunks
    int j = q - m * BPC;              // block within chunk
    int b = xcd + 8 * m;              // chunk id
    int i0 = j * 256 + threadIdx.x;
    if (i0 >= CHUNK) return;
    size_t e = (size_t)b * CHUNK + i0;
    int c = col[e];
    unsigned p = (unsigned)offs[c] + (unsigned)SP[(size_t)b * N_NODES + c]
               + (unsigned)pos[e];
    ein[p] = make_float2(__int_as_float(row[e]), w[e]);
}

// ---------------- deg from CSR (segment sum of w) -> dinv ----------------
__global__ void k_deg(const float2* __restrict__ ein, const int* __restrict__ offs,
                      float* __restrict__ dinv) {
    int idx = blockIdx.x * 256 + threadIdx.x;   // N*4
    int n = idx >> 2, l = idx & 3;
    if (n >= N_NODES) return;
    int s = offs[n], e = offs[n + 1];
    float sum = 0.f;
    for (int p = s + l; p < e; p += 4) sum += ein[p].y;
    sum += __shfl_xor(sum, 1, 4);
    sum += __shfl_xor(sum, 2, 4);
    if (l == 0) dinv[n] = rsqrtf(1.0f + sum);   // deg = 1 (self-loop) + sum >= 1
}

// ---- GEMM1 split-K=2: 128-row tile, TM4 TN4, k-chunk 32, bf16 partial out ----
__global__ __launch_bounds__(256) void k_gemm1s(const float* __restrict__ x,
                                                const float* __restrict__ W1,
                                                unsigned short* __restrict__ xwp) {
    __shared__ float sWc[32 * HID];       // 4KB
    __shared__ float sX[32 * XPAD];       // 17KB -> total 21.2KB -> 7 blocks/CU
    int t = threadIdx.x;
    long rowbase = (long)blockIdx.x * 128;
    int kbase = blockIdx.y * 128;
    unsigned short* xw = xwp + (size_t)blockIdx.y * N_NODES * HID;
    int tr = t >> 3;                      // 0..31 (4 rows each)
    int tc = t & 7;                       // 0..7  (4 cols each)
    float acc[4][4] = {};
    for (int k0 = kbase; k0 < kbase + 128; k0 += 32) {
        *(float4*)&sWc[t * 4] = *(const float4*)&W1[k0 * HID + t * 4];
        #pragma unroll
        for (int p = 0; p < 4; ++p) {
            int rt = (t >> 3) + p * 32;   // 0..127
            int kk = (t & 7) * 4;         // proven conflict-free staging class
            long grow = rowbase + rt;
            float4 v = make_float4(0.f, 0.f, 0.f, 0.f);
            if (grow < N_NODES) v = *(const float4*)&x[grow * NFEAT + k0 + kk];
            sX[(kk + 0) * XPAD + rt] = v.x; sX[(kk + 1) * XPAD + rt] = v.y;
            sX[(kk + 2) * XPAD + rt] = v.z; sX[(kk + 3) * XPAD + rt] = v.w;
        }
        __syncthreads();
        #pragma unroll 8
        for (int kk = 0; kk < 32; ++kk) {
            float xv[4], wv[4];
            xv[0] = sX[kk * XPAD + tr * 4 + 0];
            xv[1] = sX[kk * XPAD + tr * 4 + 1];
            xv[2] = sX[kk * XPAD + tr * 4 + 2];
            xv[3] = sX[kk * XPAD + tr * 4 + 3];
            *(float4*)&wv[0] = *(float4*)&sWc[kk * HID + tc * 4];
            #pragma unroll
            for (int m = 0; m < 4; ++m)
                #pragma unroll
                for (int n = 0; n < 4; ++n)
                    acc[m][n] = fmaf(xv[m], wv[n], acc[m][n]);
        }
        __syncthreads();
    }
    #pragma unroll
    for (int m = 0; m < 4; ++m) {
        long r = rowbase + tr * 4 + m;
        if (r < N_NODES) {
            ushort4 o;
            o.x = f2bf(acc[m][0]); o.y = f2bf(acc[m][1]);
            o.z = f2bf(acc[m][2]); o.w = f2bf(acc[m][3]);
            *(ushort4*)&xw[r * HID + tc * 4] = o;
        }
    }
}

// ---- combine 2 bf16 split-K partials -> bf16 gather table ----
__global__ void k_comb(const unsigned short* __restrict__ xwp,
                       ushort4* __restrict__ xwb) {
    int i = blockIdx.x * 256 + threadIdx.x;   // N*HID/4 = 800000 exact
    const ushort4* p0 = (const ushort4*)xwp;
    const ushort4* p1 = p0 + 800000;
    ushort4 a = p0[i], b = p1[i];
    ushort4 o;
    o.x = f2bf(bf2f(a.x) + bf2f(b.x));
    o.y = f2bf(bf2f(a.y) + bf2f(b.y));
    o.z = f2bf(bf2f(a.z) + bf2f(b.z));
    o.w = f2bf(bf2f(a.w) + bf2f(b.w));
    xwb[i] = o;
}

// ---- gather layer 1: 8 lanes/node, bf16 table (R12's 64us config) ----
__global__ __launch_bounds__(256) void k_gather1(const unsigned short* __restrict__ xwb,
                                                 const float* __restrict__ dinv,
                                                 const float2* __restrict__ ein,
                                                 const int* __restrict__ offs,
                                                 const float* __restrict__ b1,
                                                 float* __restrict__ h) {
    int idx = blockIdx.x * 256 + threadIdx.x;   // N*8 exact
    int n = idx >> 3, l = idx & 7;
    int c4 = l * 4;
    const ushort4* xb = (const ushort4*)xwb;    // 8 ushort4 per row
    float di = dinv[n];
    ushort4 q = xb[(long)n * 8 + l];
    float4 acc = make_float4(bf2f(q.x) * di, bf2f(q.y) * di,
                             bf2f(q.z) * di, bf2f(q.w) * di);
    int s = offs[n], e = offs[n + 1];
    for (int p0 = s; p0 < e; p0 += 8) {
        int pl = p0 + l;
        float2 pr = (pl < e) ? ein[pl] : make_float2(__int_as_float(n), 0.f);
        int ri = __float_as_int(pr.x);
        pr.y *= dinv[ri];                 // fold dinv[src] before broadcast
        #pragma unroll
        for (int j = 0; j < 8; ++j) {
            int r = __shfl(ri, j, 8);
            float nm = __shfl(pr.y, j, 8);
            ushort4 g = xb[(long)r * 8 + l];
            acc.x = fmaf(bf2f(g.x), nm, acc.x);
            acc.y = fmaf(bf2f(g.y), nm, acc.y);
            acc.z = fmaf(bf2f(g.z), nm, acc.z);
            acc.w = fmaf(bf2f(g.w), nm, acc.w);
        }
    }
    float4 bb = *(const float4*)&b1[c4];
    acc.x = fmaxf(fmaf(acc.x, di, bb.x), 0.f);
    acc.y = fmaxf(fmaf(acc.y, di, bb.y), 0.f);
    acc.z = fmaxf(fmaf(acc.z, di, bb.z), 0.f);
    acc.w = fmaxf(fmaf(acc.w, di, bb.w), 0.f);
    *(float4*)&h[(long)n * HID + c4] = acc;
}

// ---------------- GEMM2: hw = h @ W2 -> bf16 table ----------------
__global__ __launch_bounds__(256) void k_gemm2(const float* __restrict__ h,
                                               const float* __restrict__ W2,
                                               unsigned short* __restrict__ hwb) {
    __shared__ float sH[64][33];
    __shared__ float sW2[HID * NCLASS];
    int t = threadIdx.x;
    if (t < 128) {
        int idx = t * 4;
        *(float4*)&sW2[idx] = *(const float4*)&W2[idx];
    }
    long base = (long)blockIdx.x * 64;
    #pragma unroll
    for (int i = 0; i < 2; ++i) {
        int idx = t + i * 256;
        int rt = idx >> 3, kk = (idx & 7) * 4;
        long gr = base + rt;
        float4 v = make_float4(0.f, 0.f, 0.f, 0.f);
        if (gr < N_NODES) v = *(const float4*)&h[gr * HID + kk];
        sH[rt][kk + 0] = v.x; sH[rt][kk + 1] = v.y;
        sH[rt][kk + 2] = v.z; sH[rt][kk + 3] = v.w;
    }
    __syncthreads();
    int r = t >> 2, c4 = (t & 3) * 4;
    float acc[4] = {};
    #pragma unroll
    for (int k = 0; k < HID; ++k) {
        float hv = sH[r][k];
        float wv[4];
        *(float4*)&wv[0] = *(float4*)&sW2[k * NCLASS + c4];
        #pragma unroll
        for (int n = 0; n < 4; ++n) acc[n] = fmaf(hv, wv[n], acc[n]);
    }
    long gr = base + r;
    if (gr < N_NODES) {
        ushort4 o;
        o.x = f2bf(acc[0]); o.y = f2bf(acc[1]);
        o.z = f2bf(acc[2]); o.w = f2bf(acc[3]);
        *(ushort4*)&hwb[gr * NCLASS + c4] = o;
    }
}

// ---- gather layer 2: 2 lanes/node x 16B loads, 8-deep, softmax width 2 ----
__global__ __launch_bounds__(256) void k_gather2(const unsigned short* __restrict__ hwb,
                                                 const float* __restrict__ dinv,
                                                 const float2* __restrict__ ein,
                                                 const int* __restrict__ offs,
                                                 const float* __restrict__ b2,
                                                 float* __restrict__ out) {
    int idx = blockIdx.x * 256 + threadIdx.x;   // over N*2
    int n = idx >> 1, l = idx & 1;
    if (n >= N_NODES) return;
    int c8 = l * 8;
    const uint4* hb = (const uint4*)hwb;        // 2 uint4 per 16-class row
    float di = dinv[n];
    float acc[8], f[8];
    bf8_unpack(hb[(long)n * 2 + l], f);
    #pragma unroll
    for (int k = 0; k < 8; ++k) acc[k] = f[k] * di;
    int s = offs[n], e = offs[n + 1];
    for (int p0 = s; p0 < e; p0 += 8) {
        float2 pr[4];
        int rr[4];
        #pragma unroll
        for (int k = 0; k < 4; ++k) {
            int pl = p0 + k * 2 + l;
            pr[k] = (pl < e) ? ein[pl] : make_float2(__int_as_float(n), 0.f);
            rr[k] = __float_as_int(pr[k].x);
            pr[k].y *= dinv[rr[k]];
        }
        #pragma unroll
        for (int k = 0; k < 4; ++k) {
            #pragma unroll
            for (int j = 0; j < 2; ++j) {
                int r = __shfl(rr[k], j, 2);
                float nm = __shfl(pr[k].y, j, 2);
                bf8_unpack(hb[(long)r * 2 + l], f);
                #pragma unroll
                for (int q = 0; q < 8; ++q) acc[q] = fmaf(f[q], nm, acc[q]);
            }
        }
    }
    float4 bb0 = *(const float4*)&b2[c8];
    float4 bb1 = *(const float4*)&b2[c8 + 4];
    float v[8];
    v[0] = fmaf(acc[0], di, bb0.x); v[1] = fmaf(acc[1], di, bb0.y);
    v[2] = fmaf(acc[2], di, bb0.z); v[3] = fmaf(acc[3], di, bb0.w);
    v[4] = fmaf(acc[4], di, bb1.x); v[5] = fmaf(acc[5], di, bb1.y);
    v[6] = fmaf(acc[6], di, bb1.z); v[7] = fmaf(acc[7], di, bb1.w);
    float m = v[0];
    #pragma unroll
    for (int k = 1; k < 8; ++k) m = fmaxf(m, v[k]);
    m = fmaxf(m, __shfl_xor(m, 1, 2));
    float sum = 0.f;
    #pragma unroll
    for (int k = 0; k < 8; ++k) sum += __expf(v[k] - m);
    sum += __shfl_xor(sum, 1, 2);
    float ls = m + __logf(sum);
    float4 o0 = make_float4(v[0] - ls, v[1] - ls, v[2] - ls, v[3] - ls);
    float4 o1 = make_float4(v[4] - ls, v[5] - ls, v[6] - ls, v[7] - ls);
    *(float4*)&out[(long)n * NCLASS + c8] = o0;
    *(float4*)&out[(long)n * NCLASS + c8 + 4] = o1;
}

extern "C" void kernel_launch(void* const* d_in, const int* in_sizes, int n_in,
                              void* d_out, int out_size, void* d_ws, size_t ws_size,
                              hipStream_t stream) {
    const float* x  = (const float*)d_in[0];
    const int*   ei = (const int*)d_in[1];
    const float* w  = (const float*)d_in[2];
    const float* W1 = (const float*)d_in[3];
    const float* b1 = (const float*)d_in[4];
    const float* W2 = (const float*)d_in[5];
    const float* b2 = (const float*)d_in[6];
    float* out = (float*)d_out;

    const int* row = ei;
    const int* col = ei + N_EDGES;

    // Workspace (floats). Tight-aliased; ws ~100MB + inputs ~147MB < 256MB L3.
    //   pos (E u16) read last by k_emit -> h (N*HID f32) written over it after.
    //   H (u32) read last by k_prefix16; SP (u16) is separate (no alias: race).
    float* ws = (float*)d_ws;
    float2* ein = (float2*)ws;                            // 25.6MB
    unsigned* H = (unsigned*)(ws + 2 * (size_t)N_EDGES);  // NB*N u32 (25.6MB)
    unsigned short* pos = (unsigned short*)(ws + 2 * (size_t)N_EDGES + (size_t)NB * N_NODES);  // E u16
    float* h = (float*)pos;                               // alias: written after emit
    float* dinv = ws + 2 * (size_t)N_EDGES + (size_t)NB * N_NODES + N_EDGES;  // N
    int* cnt = (int*)(dinv + N_NODES);                    // N
    int* offs = cnt + N_NODES;                            // N+1
    int* bsum = offs + N_NODES + 1;                       // 128
    size_t xwp_off = (size_t)(2 * (size_t)N_EDGES + (size_t)NB * N_NODES + N_EDGES
                              + 3 * N_NODES + 1 + 128);
    xwp_off = (xwp_off + 3) & ~(size_t)3;                 // 16B align
    unsigned short* xwp = (unsigned short*)(ws + xwp_off);               // [2][N*HID] bf16 (12.8MB)
    unsigned short* xwb = (unsigned short*)(ws + xwp_off + 3200000);     // N*HID bf16 (6.4MB)
    unsigned short* hwb = xwb + (size_t)N_NODES * HID;                   // N*NCLASS bf16 (3.2MB)
    unsigned short* SP = hwb + (size_t)N_NODES * NCLASS;                 // NB*N u16 (12.8MB)

    const int B = 256;

    k_count<<<dim3(NB, NR2), 1024, 0, stream>>>(col, H, pos);
    k_prefix16<<<(N_NODES + B - 1) / B, B, 0, stream>>>(H, SP, cnt);
    k_scanA<<<SCAN_NBLK, SCAN_TPB, 0, stream>>>(cnt, offs, bsum);
    k_scanB<<<1, 128, 0, stream>>>(bsum);
    k_scanC<<<SCAN_NBLK, SCAN_TPB, 0, stream>>>(offs, bsum);
    k_emit<<<8 * 8 * BPC, B, 0, stream>>>(row, col, w, offs, SP, pos, ein);

    k_deg<<<(N_NODES * 4 + B - 1) / B, B, 0, stream>>>(ein, offs, dinv);

    k_gemm1s<<<dim3((N_NODES + 127) / 128, 2), 256, 0, stream>>>(x, W1, xwp);
    k_comb<<<(N_NODES * HID / 4) / B, B, 0, stream>>>(xwp, (ushort4*)xwb);
    k_gather1<<<(N_NODES * 8) / B, B, 0, stream>>>(xwb, dinv, ein, offs, b1, h);

    k_gemm2<<<(N_NODES + 63) / 64, B, 0, stream>>>(h, W2, hwb);
    k_gather2<<<(N_NODES * 2 + B - 1) / B, B, 0, stream>>>(hwb, dinv, ein, offs, b2, out);
}